// Round 1
// baseline (2135.042 us; speedup 1.0000x reference)
//
#include <hip/hip_runtime.h>
#include <math.h>

#define NN 50000
#define EE 640000
#define HH 128
#define KK 25000
#define NEG_SLOPE 0.2f
#define TIE_CAP 4096
#define BN_BLOCKS 200

__device__ __forceinline__ float lrelu(float x) { return x >= 0.f ? x : NEG_SLOPE * x; }
__device__ __forceinline__ float prelu(float x, float a) { return x >= 0.f ? x : a * x; }
// order-preserving float->uint map (no NaNs expected)
__device__ __forceinline__ unsigned ford(float f) {
    unsigned u = __float_as_uint(f);
    return (u & 0x80000000u) ? ~u : (u | 0x80000000u);
}
__device__ __forceinline__ float unford(unsigned u) {
    return __uint_as_float((u & 0x80000000u) ? (u & 0x7fffffffu) : ~u);
}

// ---------------- CSR build ----------------
__global__ __launch_bounds__(256) void deg_hist(const int* __restrict__ dst, int* __restrict__ deg) {
    int i = blockIdx.x * 256 + threadIdx.x;
    if (i < EE) atomicAdd(&deg[dst[i]], 1);
}

__global__ __launch_bounds__(1024) void scan_ptr(const int* __restrict__ deg, int* __restrict__ ptr,
                                                 int* __restrict__ cur) {
    __shared__ int csum[1024];
    int c = threadIdx.x;
    int b0 = c * 49, b1 = b0 + 49;
    if (b1 > NN) b1 = NN;
    int s = 0;
    for (int i = b0; i < b1; ++i) s += deg[i];
    csum[c] = s;
    __syncthreads();
    if (c == 0) {
        int acc = 0;
        for (int i = 0; i < 1024; ++i) { int t = csum[i]; csum[i] = acc; acc += t; }
        ptr[NN] = acc;
    }
    __syncthreads();
    int acc = csum[c];
    for (int i = b0; i < b1; ++i) { ptr[i] = acc; cur[i] = acc; acc += deg[i]; }
}

__global__ __launch_bounds__(256) void scatter_csr(const int* __restrict__ src, const int* __restrict__ dst,
                                                   int* __restrict__ cur, int* __restrict__ csr) {
    int i = blockIdx.x * 256 + threadIdx.x;
    if (i < EE) {
        int p = atomicAdd(&cur[dst[i]], 1);
        csr[p] = src[i];
    }
}

// ---------------- GEMM: C[n,128] = A[n,128] @ W[128,128] (+bias) (+C) ----------------
__global__ __launch_bounds__(256) void gemm128(const float* __restrict__ A, const float* __restrict__ W,
                                               const float* __restrict__ bias, float* __restrict__ C,
                                               int n, int accflag, int biasflag) {
    __shared__ float sW[128 * 128];      // 64 KB
    __shared__ float sA[32 * 132];       // padded stride 132 -> no 4-way bank conflict on row reads
    for (int i = threadIdx.x; i < 4096; i += 256)
        ((float4*)sW)[i] = ((const float4*)W)[i];
    int row0 = blockIdx.x * 32;
    int nrows = n - row0; if (nrows > 32) nrows = 32;
    for (int i = threadIdx.x; i < 1024; i += 256) {
        int r = i >> 5, c4 = i & 31;
        if (r < nrows)
            *((float4*)(sA + r * 132 + c4 * 4)) = ((const float4*)(A + (size_t)(row0 + r) * 128))[c4];
    }
    __syncthreads();
    int tr = threadIdx.x >> 4;           // 0..15 -> rows tr*2, tr*2+1
    int tc = (threadIdx.x & 15) << 3;    // col start (8 cols)
    float acc0[8] = {0,0,0,0,0,0,0,0};
    float acc1[8] = {0,0,0,0,0,0,0,0};
    const float* a0p = sA + (tr * 2) * 132;
    const float* a1p = a0p + 132;
    for (int k = 0; k < 128; ++k) {
        float a0 = a0p[k], a1 = a1p[k];
        const float* wp = sW + k * 128 + tc;
        #pragma unroll
        for (int u = 0; u < 8; ++u) {
            float wv = wp[u];
            acc0[u] = fmaf(a0, wv, acc0[u]);
            acc1[u] = fmaf(a1, wv, acc1[u]);
        }
    }
    #pragma unroll
    for (int rr = 0; rr < 2; ++rr) {
        int r = row0 + tr * 2 + rr;
        if (r < n) {
            float* op = C + (size_t)r * 128 + tc;
            #pragma unroll
            for (int u = 0; u < 8; ++u) {
                float v = rr == 0 ? acc0[u] : acc1[u];
                if (biasflag) v += bias[tc + u];
                if (accflag) v += op[u];
                op[u] = v;
            }
        }
    }
}

// ---------------- GAT ----------------
__global__ __launch_bounds__(256) void att_scores(const float* __restrict__ xw, const float* __restrict__ asrc,
                                                  const float* __restrict__ adst, float* __restrict__ ssrc,
                                                  float* __restrict__ sdst) {
    int wid = (blockIdx.x * 256 + threadIdx.x) >> 6;
    int lane = threadIdx.x & 63;
    if (wid >= NN) return;
    float x0 = xw[(size_t)wid * 128 + lane];
    float x1 = xw[(size_t)wid * 128 + lane + 64];
    float ps = x0 * asrc[lane] + x1 * asrc[lane + 64];
    float pd = x0 * adst[lane] + x1 * adst[lane + 64];
    #pragma unroll
    for (int o = 32; o; o >>= 1) { ps += __shfl_xor(ps, o); pd += __shfl_xor(pd, o); }
    if (lane == 0) { ssrc[wid] = ps; sdst[wid] = pd; }
}

__global__ __launch_bounds__(256) void gat_agg(const float* __restrict__ xw, const int* __restrict__ csr,
                                               const int* __restrict__ ptr, const float* __restrict__ ssrc,
                                               const float* __restrict__ sdst, const float* __restrict__ bias,
                                               float* __restrict__ out) {
    int wid = (blockIdx.x * 256 + threadIdx.x) >> 6;
    int lane = threadIdx.x & 63;
    if (wid >= NN) return;
    int s = ptr[wid], e = ptr[wid + 1];
    float sd = sdst[wid];
    float selfval = lrelu(ssrc[wid] + sd);
    // pass 1: max over incoming (incl. self-loop)
    float m = selfval;
    for (int i = s + lane; i < e; i += 64) m = fmaxf(m, lrelu(ssrc[csr[i]] + sd));
    #pragma unroll
    for (int o = 32; o; o >>= 1) m = fmaxf(m, __shfl_xor(m, o));
    // pass 2: sum exp
    float sum = (lane == 0) ? __expf(selfval - m) : 0.f;
    for (int i = s + lane; i < e; i += 64) sum += __expf(lrelu(ssrc[csr[i]] + sd) - m);
    #pragma unroll
    for (int o = 32; o; o >>= 1) sum += __shfl_xor(sum, o);
    float inv = 1.f / sum;
    // pass 3: feature max of alpha * xw[src]
    float aself = __expf(selfval - m) * inv;
    float f0 = aself * xw[(size_t)wid * 128 + lane];
    float f1 = aself * xw[(size_t)wid * 128 + lane + 64];
    for (int i = s; i < e; ++i) {
        int src = csr[i];
        float a = __expf(lrelu(ssrc[src] + sd) - m) * inv;
        f0 = fmaxf(f0, a * xw[(size_t)src * 128 + lane]);
        f1 = fmaxf(f1, a * xw[(size_t)src * 128 + lane + 64]);
    }
    out[(size_t)wid * 128 + lane] = f0 + bias[lane];
    out[(size_t)wid * 128 + lane + 64] = f1 + bias[lane + 64];
}

// ---------------- BatchNorm (batch stats) + PReLU ----------------
__global__ __launch_bounds__(256) void bn_stage1(const float* __restrict__ x, float* __restrict__ psum,
                                                 float* __restrict__ psq) {
    int col = threadIdx.x & 127, sub = threadIdx.x >> 7;
    int r0 = blockIdx.x * 250, r1 = r0 + 250;
    float s = 0.f, q = 0.f;
    for (int r = r0 + sub; r < r1; r += 2) {
        float v = x[(size_t)r * 128 + col];
        s += v;
        q = fmaf(v, v, q);
    }
    __shared__ float ls[256], lq[256];
    ls[threadIdx.x] = s; lq[threadIdx.x] = q;
    __syncthreads();
    if (sub == 0) {
        psum[blockIdx.x * 128 + col] = ls[col] + ls[col + 128];
        psq[blockIdx.x * 128 + col] = lq[col] + lq[col + 128];
    }
}

__global__ __launch_bounds__(128) void bn_stage2(const float* __restrict__ psum, const float* __restrict__ psq,
                                                 const float* __restrict__ w, const float* __restrict__ b,
                                                 float* __restrict__ scale, float* __restrict__ shift) {
    int c = threadIdx.x;
    double s = 0.0, q = 0.0;
    for (int i = 0; i < BN_BLOCKS; ++i) { s += (double)psum[i * 128 + c]; q += (double)psq[i * 128 + c]; }
    double mu = s / NN;
    double var = q / NN - mu * mu;
    if (var < 0.0) var = 0.0;
    float rs = (float)(1.0 / sqrt(var + 1e-5));
    float sc = rs * w[c];
    scale[c] = sc;
    shift[c] = b[c] - (float)mu * sc;
}

__global__ __launch_bounds__(256) void bn_prelu_apply(float* __restrict__ x, const float* __restrict__ scale,
                                                      const float* __restrict__ shift, const float* __restrict__ pa) {
    int i = blockIdx.x * 256 + threadIdx.x;   // grid covers NN*128/4 exactly
    float a = pa[0];
    float4 v = ((float4*)x)[i];
    int c = (i * 4) & 127;
    v.x = v.x * scale[c]     + shift[c];     v.x = prelu(v.x, a);
    v.y = v.y * scale[c + 1] + shift[c + 1]; v.y = prelu(v.y, a);
    v.z = v.z * scale[c + 2] + shift[c + 2]; v.z = prelu(v.z, a);
    v.w = v.w * scale[c + 3] + shift[c + 3]; v.w = prelu(v.w, a);
    ((float4*)x)[i] = v;
}

// ---------------- SAGE: out = maxagg(h1) @ wl  (wr/bias added by gemm128 acc pass) ----------------
__global__ __launch_bounds__(256) void sage_s1(const float* __restrict__ h1, const int* __restrict__ csr,
                                               const int* __restrict__ ptr, const float* __restrict__ wl,
                                               float* __restrict__ outp) {
    __shared__ float sW[128 * 128];
    __shared__ float sAgg[4][128];
    for (int i = threadIdx.x; i < 4096; i += 256) ((float4*)sW)[i] = ((const float4*)wl)[i];
    __syncthreads();
    int lw = threadIdx.x >> 6, lane = threadIdx.x & 63;
    for (int d = blockIdx.x * 4 + lw; d < NN; d += gridDim.x * 4) {
        int s = ptr[d], e = ptr[d + 1];
        float m0 = -INFINITY, m1 = -INFINITY;
        for (int i = s; i < e; ++i) {
            int src = csr[i];
            m0 = fmaxf(m0, h1[(size_t)src * 128 + lane]);
            m1 = fmaxf(m1, h1[(size_t)src * 128 + lane + 64]);
        }
        if (s == e) { m0 = 0.f; m1 = 0.f; }   // isolated nodes -> 0
        sAgg[lw][lane] = m0;
        sAgg[lw][lane + 64] = m1;
        float y0 = 0.f, y1 = 0.f;
        for (int k = 0; k < 128; ++k) {
            float a = sAgg[lw][k];
            y0 = fmaf(a, sW[k * 128 + lane], y0);
            y1 = fmaf(a, sW[k * 128 + lane + 64], y1);
        }
        outp[(size_t)d * 128 + lane] = y0;
        outp[(size_t)d * 128 + lane + 64] = y1;
    }
}

// ---------------- SAGPool score ----------------
__global__ __launch_bounds__(256) void pool_score(const float* __restrict__ h2, const int* __restrict__ csr,
                                                  const int* __restrict__ ptr, const float* __restrict__ wrel,
                                                  const float* __restrict__ wroot, const float* __restrict__ brel,
                                                  float* __restrict__ score, unsigned* __restrict__ su) {
    int wid = (blockIdx.x * 256 + threadIdx.x) >> 6;
    int lane = threadIdx.x & 63;
    if (wid >= NN) return;
    int s = ptr[wid], e = ptr[wid + 1];
    float a0 = 0.f, a1 = 0.f;
    for (int i = s; i < e; ++i) {
        int src = csr[i];
        a0 += h2[(size_t)src * 128 + lane];
        a1 += h2[(size_t)src * 128 + lane + 64];
    }
    float part = a0 * wrel[lane] + a1 * wrel[lane + 64]
               + h2[(size_t)wid * 128 + lane] * wroot[lane]
               + h2[(size_t)wid * 128 + lane + 64] * wroot[lane + 64];
    #pragma unroll
    for (int o = 32; o; o >>= 1) part += __shfl_xor(part, o);
    if (lane == 0) {
        float sc = part + brel[0];
        score[wid] = sc;
        su[wid] = ford(sc);
    }
}

// ---------------- exact K-th largest (radix 2x16-bit) ----------------
__global__ __launch_bounds__(256) void hist_hi_k(const unsigned* __restrict__ su, unsigned* __restrict__ hist) {
    int i = blockIdx.x * 256 + threadIdx.x;
    if (i < NN) atomicAdd(&hist[su[i] >> 16], 1u);
}

__global__ __launch_bounds__(1024) void scan_hi(const unsigned* __restrict__ hist, unsigned* __restrict__ selst) {
    __shared__ unsigned csum[1024];
    int c = threadIdx.x;
    unsigned s = 0;
    const unsigned* hp = hist + c * 64;
    for (int j = 0; j < 64; ++j) s += hp[j];
    csum[c] = s;
    __syncthreads();
    if (c == 0) {
        unsigned cum = 0;
        int chunk = 1023;
        for (; chunk > 0; --chunk) { if (cum + csum[chunk] >= KK) break; cum += csum[chunk]; }
        int b = chunk * 64 + 63;
        for (; b > chunk * 64; --b) { if (cum + hist[b] >= KK) break; cum += hist[b]; }
        selst[0] = (unsigned)b;   // hi bin of K-th largest
        selst[1] = cum;           // count strictly above hi bin
    }
}

__global__ __launch_bounds__(256) void hist_lo_k(const unsigned* __restrict__ su, const unsigned* __restrict__ selst,
                                                 unsigned* __restrict__ histlo) {
    int i = blockIdx.x * 256 + threadIdx.x;
    if (i < NN) {
        unsigned u = su[i];
        if ((u >> 16) == selst[0]) atomicAdd(&histlo[u & 0xffffu], 1u);
    }
}

__global__ __launch_bounds__(1024) void scan_lo(const unsigned* __restrict__ histlo, unsigned* __restrict__ selst) {
    __shared__ unsigned csum[1024];
    int c = threadIdx.x;
    unsigned s = 0;
    const unsigned* hp = histlo + c * 64;
    for (int j = 0; j < 64; ++j) s += hp[j];
    csum[c] = s;
    __syncthreads();
    if (c == 0) {
        unsigned cum = selst[1];
        int chunk = 1023;
        for (; chunk > 0; --chunk) { if (cum + csum[chunk] >= KK) break; cum += csum[chunk]; }
        int b = chunk * 64 + 63;
        for (; b > chunk * 64; --b) { if (cum + histlo[b] >= KK) break; cum += histlo[b]; }
        unsigned tu = (selst[0] << 16) | (unsigned)b;
        selst[2] = tu;          // K-th largest value (ordered uint)
        selst[3] = KK - cum;    // R = how many ties (==tu) to take, smallest indices first
    }
}

// ---------------- selection + per-column max of tanh(score)*h2 ----------------
__global__ __launch_bounds__(256) void select_colmax(const float* __restrict__ h2, const float* __restrict__ score,
                                                     const unsigned* __restrict__ su, const unsigned* __restrict__ selst,
                                                     unsigned* __restrict__ ties, unsigned* __restrict__ tiecnt,
                                                     unsigned* __restrict__ colmax) {
    unsigned tu = selst[2];
    int col = threadIdx.x & 127, sub = threadIdx.x >> 7;
    int r0 = blockIdx.x * 250, r1 = r0 + 250;
    float m = -INFINITY;
    for (int r = r0 + sub; r < r1; r += 2) {
        unsigned u = su[r];
        if (u > tu) {
            float g = tanhf(score[r]);
            m = fmaxf(m, g * h2[(size_t)r * 128 + col]);
        } else if (u == tu && col == 0) {
            unsigned p = atomicAdd(tiecnt, 1u);
            if (p < TIE_CAP) ties[p] = (unsigned)r;
        }
    }
    __shared__ float ls[256];
    ls[threadIdx.x] = m;
    __syncthreads();
    if (sub == 0) {
        float mm = fmaxf(ls[col], ls[col + 128]);
        if (mm > -INFINITY) atomicMax(&colmax[col], ford(mm));
    }
}

__global__ __launch_bounds__(128) void tie_resolve(const float* __restrict__ h2, const float* __restrict__ score,
                                                   const unsigned* __restrict__ selst, const unsigned* __restrict__ ties,
                                                   unsigned* __restrict__ colmax) {
    __shared__ unsigned chosen;
    int R = (int)selst[3];
    int tc = (int)selst[4];
    if (tc > TIE_CAP) tc = TIE_CAP;
    int t = threadIdx.x;
    unsigned last = 0;
    int iters = R < tc ? R : tc;
    for (int it = 0; it < iters; ++it) {
        if (t == 0) {
            unsigned best = 0xffffffffu;
            for (int j = 0; j < tc; ++j) {
                unsigned v = ties[j];
                if (v >= last && v < best) best = v;
            }
            chosen = best;
        }
        __syncthreads();
        unsigned row = chosen;
        if (row != 0xffffffffu) {
            float g = tanhf(score[row]);
            atomicMax(&colmax[t], ford(g * h2[(size_t)row * 128 + t]));
        }
        __syncthreads();
        if (t == 0) last = chosen + 1;
    }
}

// ---------------- head MLP (1 block) ----------------
__global__ __launch_bounds__(128) void head_k(const unsigned* __restrict__ colmax, const float* __restrict__ addf,
                                              const float* __restrict__ fc1w, const float* __restrict__ fc1b,
                                              const float* __restrict__ fa1, const float* __restrict__ w21,
                                              const float* __restrict__ b21, const float* __restrict__ fa2,
                                              const float* __restrict__ w22, const float* __restrict__ b22,
                                              const float* __restrict__ w3, const float* __restrict__ b3,
                                              const float* __restrict__ wm, const float* __restrict__ bm,
                                              float* __restrict__ out) {
    __shared__ float ag[132], xv[128], yv[128], red0[128], red1[128], red2[128];
    int t = threadIdx.x;
    ag[t] = fmaxf(unford(colmax[t]), unford(colmax[128 + t]));
    if (t < 4) ag[128 + t] = addf[t];
    __syncthreads();
    float s = fc1b[t];
    for (int k = 0; k < 132; ++k) s = fmaf(ag[k], fc1w[k * 128 + t], s);
    xv[t] = prelu(s, fa1[0]);
    __syncthreads();
    float s2 = b21[t];
    for (int k = 0; k < 128; ++k) s2 = fmaf(xv[k], w21[k * 128 + t], s2);
    yv[t] = prelu(s2, fa2[0]);
    __syncthreads();
    red0[t] = yv[t] * w22[t];
    red1[t] = xv[t] * w3[t];
    red2[t] = xv[t] * wm[t];
    __syncthreads();
    if (t == 0) {
        float r0 = 0.f, r1 = 0.f, r2 = 0.f;
        for (int k = 0; k < 128; ++k) { r0 += red0[k]; r1 += red1[k]; r2 += red2[k]; }
        out[0] = expf(r0 + b22[0]);
        out[1] = expf(r1 + b3[0]) * tanhf(r2 + bm[0]);
    }
}

extern "C" void kernel_launch(void* const* d_in, const int* in_sizes, int n_in,
                              void* d_out, int out_size, void* d_ws, size_t ws_size,
                              hipStream_t stream) {
    const float* Ax    = (const float*)d_in[0];
    const float* Gx    = (const float*)d_in[1];
    const float* addf  = (const float*)d_in[2];
    const float* gatw  = (const float*)d_in[3];
    const float* asrc  = (const float*)d_in[4];
    const float* adst  = (const float*)d_in[5];
    const float* gbias = (const float*)d_in[6];
    const float* bn1w  = (const float*)d_in[7];
    const float* bn1b  = (const float*)d_in[8];
    const float* pa1   = (const float*)d_in[9];
    const float* wl    = (const float*)d_in[10];
    const float* bl    = (const float*)d_in[11];
    const float* wr    = (const float*)d_in[12];
    const float* bn2w  = (const float*)d_in[13];
    const float* bn2b  = (const float*)d_in[14];
    const float* pa2   = (const float*)d_in[15];
    const float* wrel  = (const float*)d_in[16];
    const float* brel  = (const float*)d_in[17];
    const float* wroot = (const float*)d_in[18];
    const float* fc1w  = (const float*)d_in[19];
    const float* fc1b  = (const float*)d_in[20];
    const float* fa1   = (const float*)d_in[21];
    const float* w21   = (const float*)d_in[22];
    const float* b21   = (const float*)d_in[23];
    const float* fa2   = (const float*)d_in[24];
    const float* w22   = (const float*)d_in[25];
    const float* b22   = (const float*)d_in[26];
    const float* w3    = (const float*)d_in[27];
    const float* b3    = (const float*)d_in[28];
    const float* wm    = (const float*)d_in[29];
    const float* bm    = (const float*)d_in[30];
    const int*   Aei   = (const int*)d_in[31];
    const int*   Gei   = (const int*)d_in[32];
    float* out = (float*)d_out;

    char* wp = (char*)d_ws;
    auto alloc = [&](size_t bytes) -> char* {
        char* p = wp;
        wp += (bytes + 255) & ~(size_t)255;
        return p;
    };
    float*    big1   = (float*)alloc((size_t)NN * HH * 4);   // xw, then SAGE/h2
    float*    big2   = (float*)alloc((size_t)NN * HH * 4);   // h1
    int*      csr    = (int*)alloc((size_t)EE * 4);
    int*      ptr    = (int*)alloc((NN + 1) * 4);
    int*      cur    = (int*)alloc(NN * 4);
    int*      deg    = (int*)alloc(NN * 4);
    float*    ssrc   = (float*)alloc(NN * 4);
    float*    sdst   = (float*)alloc(NN * 4);
    float*    score  = (float*)alloc(NN * 4);
    unsigned* su     = (unsigned*)alloc(NN * 4);
    float*    psum   = (float*)alloc(BN_BLOCKS * 128 * 4);
    float*    psq    = (float*)alloc(BN_BLOCKS * 128 * 4);
    float*    scale  = (float*)alloc(128 * 4);
    float*    shift  = (float*)alloc(128 * 4);
    unsigned* hist   = (unsigned*)alloc(65536 * 4);
    unsigned* histlo = (unsigned*)alloc(65536 * 4);
    unsigned* selst  = (unsigned*)alloc(8 * 4);
    unsigned* ties   = (unsigned*)alloc(TIE_CAP * 4);
    unsigned* colmax = (unsigned*)alloc(2 * 128 * 4);

    hipMemsetAsync(colmax, 0, 2 * 128 * 4, stream);

    for (int t = 0; t < 2; ++t) {
        const float* x   = (t == 0) ? Ax : Gx;
        const int* ei    = (t == 0) ? Aei : Gei;
        const int* esrc  = ei;
        const int* edst  = ei + EE;

        hipMemsetAsync(deg, 0, NN * 4, stream);
        hipMemsetAsync(hist, 0, 65536 * 4, stream);
        hipMemsetAsync(histlo, 0, 65536 * 4, stream);
        hipMemsetAsync(selst, 0, 8 * 4, stream);

        deg_hist<<<EE / 256, 256, 0, stream>>>(edst, deg);
        scan_ptr<<<1, 1024, 0, stream>>>(deg, ptr, cur);
        scatter_csr<<<EE / 256, 256, 0, stream>>>(esrc, edst, cur, csr);

        // GAT
        gemm128<<<(NN + 31) / 32, 256, 0, stream>>>(x, gatw, nullptr, big1, NN, 0, 0);
        att_scores<<<(NN + 3) / 4, 256, 0, stream>>>(big1, asrc, adst, ssrc, sdst);
        gat_agg<<<(NN + 3) / 4, 256, 0, stream>>>(big1, csr, ptr, ssrc, sdst, gbias, big2);
        bn_stage1<<<BN_BLOCKS, 256, 0, stream>>>(big2, psum, psq);
        bn_stage2<<<1, 128, 0, stream>>>(psum, psq, bn1w, bn1b, scale, shift);
        bn_prelu_apply<<<NN * 128 / 4 / 256, 256, 0, stream>>>(big2, scale, shift, pa1);

        // SAGE
        sage_s1<<<1024, 256, 0, stream>>>(big2, csr, ptr, wl, big1);
        gemm128<<<(NN + 31) / 32, 256, 0, stream>>>(big2, wr, bl, big1, NN, 1, 1);
        bn_stage1<<<BN_BLOCKS, 256, 0, stream>>>(big1, psum, psq);
        bn_stage2<<<1, 128, 0, stream>>>(psum, psq, bn2w, bn2b, scale, shift);
        bn_prelu_apply<<<NN * 128 / 4 / 256, 256, 0, stream>>>(big1, scale, shift, pa2);

        // SAGPool -> column max
        pool_score<<<(NN + 3) / 4, 256, 0, stream>>>(big1, csr, ptr, wrel, wroot, brel, score, su);
        hist_hi_k<<<(NN + 255) / 256, 256, 0, stream>>>(su, hist);
        scan_hi<<<1, 1024, 0, stream>>>(hist, selst);
        hist_lo_k<<<(NN + 255) / 256, 256, 0, stream>>>(su, selst, histlo);
        scan_lo<<<1, 1024, 0, stream>>>(histlo, selst);
        select_colmax<<<200, 256, 0, stream>>>(big1, score, su, selst, ties, selst + 4, colmax + t * 128);
        tie_resolve<<<1, 128, 0, stream>>>(big1, score, selst, ties, colmax + t * 128);
    }

    head_k<<<1, 128, 0, stream>>>(colmax, addf, fc1w, fc1b, fa1, w21, b21, fa2,
                                  w22, b22, w3, b3, wm, bm, out);
}

// Round 2
// 1635.378 us; speedup vs baseline: 1.3055x; 1.3055x over previous
//
#include <hip/hip_runtime.h>
#include <math.h>

#define NN 50000
#define EE 640000
#define HH 128
#define KK 25000
#define NEG_SLOPE 0.2f
#define TIE_CAP 4096
#define BN_BLOCKS 200

__device__ __forceinline__ float lrelu(float x) { return x >= 0.f ? x : NEG_SLOPE * x; }
__device__ __forceinline__ float prelu(float x, float a) { return x >= 0.f ? x : a * x; }
// order-preserving float->uint map (no NaNs expected)
__device__ __forceinline__ unsigned ford(float f) {
    unsigned u = __float_as_uint(f);
    return (u & 0x80000000u) ? ~u : (u | 0x80000000u);
}
__device__ __forceinline__ float unford(unsigned u) {
    return __uint_as_float((u & 0x80000000u) ? (u & 0x7fffffffu) : ~u);
}

// ---------------- CSR build ----------------
__global__ __launch_bounds__(256) void deg_hist(const int* __restrict__ dst, int* __restrict__ deg) {
    int i = blockIdx.x * 256 + threadIdx.x;
    if (i < EE) atomicAdd(&deg[dst[i]], 1);
}

__global__ __launch_bounds__(1024) void scan_ptr(const int* __restrict__ deg, int* __restrict__ ptr,
                                                 int* __restrict__ cur) {
    __shared__ int csum[1024];
    int c = threadIdx.x;
    int b0 = c * 49, b1 = b0 + 49;
    if (b1 > NN) b1 = NN;
    int s = 0;
    for (int i = b0; i < b1; ++i) s += deg[i];
    csum[c] = s;
    __syncthreads();
    if (c == 0) {
        int acc = 0;
        for (int i = 0; i < 1024; ++i) { int t = csum[i]; csum[i] = acc; acc += t; }
        ptr[NN] = acc;
    }
    __syncthreads();
    int acc = csum[c];
    for (int i = b0; i < b1; ++i) { ptr[i] = acc; cur[i] = acc; acc += deg[i]; }
}

__global__ __launch_bounds__(256) void scatter_csr(const int* __restrict__ src, const int* __restrict__ dst,
                                                   int* __restrict__ cur, int* __restrict__ csr) {
    int i = blockIdx.x * 256 + threadIdx.x;
    if (i < EE) {
        int p = atomicAdd(&cur[dst[i]], 1);
        csr[p] = src[i];
    }
}

// ---------------- GEMM: C[n,128] = A[n,128] @ W[128,128] (+bias) (+C) ----------------
// Safe for C == A (in-place): each block stages its 32 rows to LDS before any write.
// Column map: lane owns cols [c0,c0+4) and [c0+64,c0+68), c0=(tid&15)*4 ->
// LDS reads are 16 addrs x 16B spanning 256B = 2-way bank alias (free on CDNA4).
__global__ __launch_bounds__(256) void gemm128(const float* __restrict__ A, const float* __restrict__ W,
                                               const float* __restrict__ bias, float* __restrict__ C,
                                               int n, int accflag, int biasflag) {
    __shared__ float sW[128 * 128];      // 64 KB
    __shared__ float sA[32 * 132];
    for (int i = threadIdx.x; i < 4096; i += 256)
        ((float4*)sW)[i] = ((const float4*)W)[i];
    int row0 = blockIdx.x * 32;
    int nrows = n - row0; if (nrows > 32) nrows = 32;
    for (int i = threadIdx.x; i < 1024; i += 256) {
        int r = i >> 5, c4 = i & 31;
        if (r < nrows)
            *((float4*)(sA + r * 132 + c4 * 4)) = ((const float4*)(A + (size_t)(row0 + r) * 128))[c4];
    }
    __syncthreads();
    int tr = threadIdx.x >> 4;           // 0..15 -> rows 2tr, 2tr+1
    int c0 = (threadIdx.x & 15) * 4;
    float a00[4] = {0,0,0,0}, a01[4] = {0,0,0,0}, a10[4] = {0,0,0,0}, a11[4] = {0,0,0,0};
    const float* a0p = sA + (tr * 2) * 132;
    const float* a1p = a0p + 132;
    for (int k = 0; k < 128; ++k) {
        float a0 = a0p[k], a1 = a1p[k];
        float4 w0 = *(const float4*)(sW + k * 128 + c0);
        float4 w1 = *(const float4*)(sW + k * 128 + c0 + 64);
        a00[0] = fmaf(a0, w0.x, a00[0]); a00[1] = fmaf(a0, w0.y, a00[1]);
        a00[2] = fmaf(a0, w0.z, a00[2]); a00[3] = fmaf(a0, w0.w, a00[3]);
        a01[0] = fmaf(a0, w1.x, a01[0]); a01[1] = fmaf(a0, w1.y, a01[1]);
        a01[2] = fmaf(a0, w1.z, a01[2]); a01[3] = fmaf(a0, w1.w, a01[3]);
        a10[0] = fmaf(a1, w0.x, a10[0]); a10[1] = fmaf(a1, w0.y, a10[1]);
        a10[2] = fmaf(a1, w0.z, a10[2]); a10[3] = fmaf(a1, w0.w, a10[3]);
        a11[0] = fmaf(a1, w1.x, a11[0]); a11[1] = fmaf(a1, w1.y, a11[1]);
        a11[2] = fmaf(a1, w1.z, a11[2]); a11[3] = fmaf(a1, w1.w, a11[3]);
    }
    float b0[4] = {0,0,0,0}, b1[4] = {0,0,0,0};
    if (biasflag) {
        #pragma unroll
        for (int u = 0; u < 4; ++u) { b0[u] = bias[c0 + u]; b1[u] = bias[c0 + 64 + u]; }
    }
    #pragma unroll
    for (int rr = 0; rr < 2; ++rr) {
        int r = row0 + tr * 2 + rr;
        if (r < n) {
            float* op = C + (size_t)r * 128;
            float vlo[4], vhi[4];
            #pragma unroll
            for (int u = 0; u < 4; ++u) {
                vlo[u] = (rr ? a10[u] : a00[u]) + b0[u];
                vhi[u] = (rr ? a11[u] : a01[u]) + b1[u];
            }
            if (accflag) {
                float4 o0 = *(float4*)(op + c0);
                float4 o1 = *(float4*)(op + c0 + 64);
                vlo[0] += o0.x; vlo[1] += o0.y; vlo[2] += o0.z; vlo[3] += o0.w;
                vhi[0] += o1.x; vhi[1] += o1.y; vhi[2] += o1.z; vhi[3] += o1.w;
            }
            *(float4*)(op + c0)      = make_float4(vlo[0], vlo[1], vlo[2], vlo[3]);
            *(float4*)(op + c0 + 64) = make_float4(vhi[0], vhi[1], vhi[2], vhi[3]);
        }
    }
}

// ---------------- GAT ----------------
__global__ __launch_bounds__(256) void att_scores(const float* __restrict__ xw, const float* __restrict__ asrc,
                                                  const float* __restrict__ adst, float* __restrict__ ssrc,
                                                  float* __restrict__ sdst) {
    int wid = (blockIdx.x * 256 + threadIdx.x) >> 6;
    int lane = threadIdx.x & 63;
    if (wid >= NN) return;
    float x0 = xw[(size_t)wid * 128 + lane];
    float x1 = xw[(size_t)wid * 128 + lane + 64];
    float ps = x0 * asrc[lane] + x1 * asrc[lane + 64];
    float pd = x0 * adst[lane] + x1 * adst[lane + 64];
    #pragma unroll
    for (int o = 32; o; o >>= 1) { ps += __shfl_xor(ps, o); pd += __shfl_xor(pd, o); }
    if (lane == 0) { ssrc[wid] = ps; sdst[wid] = pd; }
}

__global__ __launch_bounds__(256) void gat_agg(const float* __restrict__ xw, const int* __restrict__ csr,
                                               const int* __restrict__ ptr, const float* __restrict__ ssrc,
                                               const float* __restrict__ sdst, const float* __restrict__ bias,
                                               float* __restrict__ ealpha, float* __restrict__ out) {
    int wid = (blockIdx.x * 256 + threadIdx.x) >> 6;
    int lane = threadIdx.x & 63;
    if (wid >= NN) return;
    int s = ptr[wid], e = ptr[wid + 1];
    float sd = sdst[wid];
    float selfval = lrelu(ssrc[wid] + sd);
    // pass 1: max over incoming (incl. self-loop)
    float m = selfval;
    for (int i = s + lane; i < e; i += 64) m = fmaxf(m, lrelu(ssrc[csr[i]] + sd));
    #pragma unroll
    for (int o = 32; o; o >>= 1) m = fmaxf(m, __shfl_xor(m, o));
    // pass 2: sum exp (cache per-edge exp to ealpha)
    float sum = (lane == 0) ? __expf(selfval - m) : 0.f;
    for (int i = s + lane; i < e; i += 64) {
        float ex = __expf(lrelu(ssrc[csr[i]] + sd) - m);
        ealpha[i] = ex;
        sum += ex;
    }
    #pragma unroll
    for (int o = 32; o; o >>= 1) sum += __shfl_xor(sum, o);
    float inv = 1.f / sum;
    // pass 3: feature max of alpha * xw[src], unrolled x4 for ILP
    float aself = __expf(selfval - m) * inv;
    float f0 = aself * xw[(size_t)wid * 128 + lane];
    float f1 = aself * xw[(size_t)wid * 128 + lane + 64];
    int i = s;
    for (; i + 4 <= e; i += 4) {
        int s0 = csr[i], s1 = csr[i + 1], s2 = csr[i + 2], s3 = csr[i + 3];
        float al0 = ealpha[i] * inv, al1 = ealpha[i + 1] * inv;
        float al2 = ealpha[i + 2] * inv, al3 = ealpha[i + 3] * inv;
        const float* p0 = xw + (size_t)s0 * 128;
        const float* p1 = xw + (size_t)s1 * 128;
        const float* p2 = xw + (size_t)s2 * 128;
        const float* p3 = xw + (size_t)s3 * 128;
        float x00 = p0[lane], x01 = p0[lane + 64];
        float x10 = p1[lane], x11 = p1[lane + 64];
        float x20 = p2[lane], x21 = p2[lane + 64];
        float x30 = p3[lane], x31 = p3[lane + 64];
        f0 = fmaxf(fmaxf(fmaxf(fmaxf(f0, al0 * x00), al1 * x10), al2 * x20), al3 * x30);
        f1 = fmaxf(fmaxf(fmaxf(fmaxf(f1, al0 * x01), al1 * x11), al2 * x21), al3 * x31);
    }
    for (; i < e; ++i) {
        int src = csr[i];
        float a = ealpha[i] * inv;
        f0 = fmaxf(f0, a * xw[(size_t)src * 128 + lane]);
        f1 = fmaxf(f1, a * xw[(size_t)src * 128 + lane + 64]);
    }
    out[(size_t)wid * 128 + lane] = f0 + bias[lane];
    out[(size_t)wid * 128 + lane + 64] = f1 + bias[lane + 64];
}

// ---------------- BatchNorm (batch stats) + PReLU ----------------
__global__ __launch_bounds__(256) void bn_stage1(const float* __restrict__ x, float* __restrict__ psum,
                                                 float* __restrict__ psq) {
    int col = threadIdx.x & 127, sub = threadIdx.x >> 7;
    int r0 = blockIdx.x * 250, r1 = r0 + 250;
    float s = 0.f, q = 0.f;
    for (int r = r0 + sub; r < r1; r += 2) {
        float v = x[(size_t)r * 128 + col];
        s += v;
        q = fmaf(v, v, q);
    }
    __shared__ float ls[256], lq[256];
    ls[threadIdx.x] = s; lq[threadIdx.x] = q;
    __syncthreads();
    if (sub == 0) {
        psum[blockIdx.x * 128 + col] = ls[col] + ls[col + 128];
        psq[blockIdx.x * 128 + col] = lq[col] + lq[col + 128];
    }
}

__global__ __launch_bounds__(128) void bn_stage2(const float* __restrict__ psum, const float* __restrict__ psq,
                                                 const float* __restrict__ w, const float* __restrict__ b,
                                                 float* __restrict__ scale, float* __restrict__ shift) {
    int c = threadIdx.x;
    double s = 0.0, q = 0.0;
    for (int i = 0; i < BN_BLOCKS; ++i) { s += (double)psum[i * 128 + c]; q += (double)psq[i * 128 + c]; }
    double mu = s / NN;
    double var = q / NN - mu * mu;
    if (var < 0.0) var = 0.0;
    float rs = (float)(1.0 / sqrt(var + 1e-5));
    float sc = rs * w[c];
    scale[c] = sc;
    shift[c] = b[c] - (float)mu * sc;
}

__global__ __launch_bounds__(256) void bn_prelu_apply(float* __restrict__ x, const float* __restrict__ scale,
                                                      const float* __restrict__ shift, const float* __restrict__ pa) {
    int i = blockIdx.x * 256 + threadIdx.x;   // grid covers NN*128/4 exactly
    float a = pa[0];
    float4 v = ((float4*)x)[i];
    int c = (i * 4) & 127;
    v.x = v.x * scale[c]     + shift[c];     v.x = prelu(v.x, a);
    v.y = v.y * scale[c + 1] + shift[c + 1]; v.y = prelu(v.y, a);
    v.z = v.z * scale[c + 2] + shift[c + 2]; v.z = prelu(v.z, a);
    v.w = v.w * scale[c + 3] + shift[c + 3]; v.w = prelu(v.w, a);
    ((float4*)x)[i] = v;
}

// ---------------- SAGE max-aggregation (no LDS -> high occupancy, x4 edge ILP) ----------------
__global__ __launch_bounds__(256) void max_agg(const float* __restrict__ h1, const int* __restrict__ csr,
                                               const int* __restrict__ ptr, float* __restrict__ agg) {
    int wid = (blockIdx.x * 256 + threadIdx.x) >> 6;
    int lane = threadIdx.x & 63;
    if (wid >= NN) return;
    int s = ptr[wid], e = ptr[wid + 1];
    float m0 = -INFINITY, m1 = -INFINITY;
    int i = s;
    for (; i + 4 <= e; i += 4) {
        int s0 = csr[i], s1 = csr[i + 1], s2 = csr[i + 2], s3 = csr[i + 3];
        const float* p0 = h1 + (size_t)s0 * 128;
        const float* p1 = h1 + (size_t)s1 * 128;
        const float* p2 = h1 + (size_t)s2 * 128;
        const float* p3 = h1 + (size_t)s3 * 128;
        float x00 = p0[lane], x01 = p0[lane + 64];
        float x10 = p1[lane], x11 = p1[lane + 64];
        float x20 = p2[lane], x21 = p2[lane + 64];
        float x30 = p3[lane], x31 = p3[lane + 64];
        m0 = fmaxf(fmaxf(fmaxf(fmaxf(m0, x00), x10), x20), x30);
        m1 = fmaxf(fmaxf(fmaxf(fmaxf(m1, x01), x11), x21), x31);
    }
    for (; i < e; ++i) {
        int src = csr[i];
        m0 = fmaxf(m0, h1[(size_t)src * 128 + lane]);
        m1 = fmaxf(m1, h1[(size_t)src * 128 + lane + 64]);
    }
    if (s == e) { m0 = 0.f; m1 = 0.f; }   // isolated nodes -> 0
    agg[(size_t)wid * 128 + lane] = m0;
    agg[(size_t)wid * 128 + lane + 64] = m1;
}

// ---------------- SAGPool score (linearized: per-node scalars, then 4B/edge gather) ----------------
__global__ __launch_bounds__(256) void node_dots(const float* __restrict__ h2, const float* __restrict__ wrel,
                                                 const float* __restrict__ wroot, float* __restrict__ pr,
                                                 float* __restrict__ rootdot) {
    int wid = (blockIdx.x * 256 + threadIdx.x) >> 6;
    int lane = threadIdx.x & 63;
    if (wid >= NN) return;
    float x0 = h2[(size_t)wid * 128 + lane];
    float x1 = h2[(size_t)wid * 128 + lane + 64];
    float p = x0 * wrel[lane] + x1 * wrel[lane + 64];
    float r = x0 * wroot[lane] + x1 * wroot[lane + 64];
    #pragma unroll
    for (int o = 32; o; o >>= 1) { p += __shfl_xor(p, o); r += __shfl_xor(r, o); }
    if (lane == 0) { pr[wid] = p; rootdot[wid] = r; }
}

__global__ __launch_bounds__(256) void score_k(const float* __restrict__ pr, const float* __restrict__ rootdot,
                                               const int* __restrict__ csr, const int* __restrict__ ptr,
                                               const float* __restrict__ brel, float* __restrict__ score,
                                               unsigned* __restrict__ su) {
    int d = blockIdx.x * 256 + threadIdx.x;
    if (d >= NN) return;
    int s = ptr[d], e = ptr[d + 1];
    float acc = 0.f;
    for (int i = s; i < e; ++i) acc += pr[csr[i]];
    float sc = acc + rootdot[d] + brel[0];
    score[d] = sc;
    su[d] = ford(sc);
}

// ---------------- exact K-th largest (radix 2x16-bit) ----------------
__global__ __launch_bounds__(256) void hist_hi_k(const unsigned* __restrict__ su, unsigned* __restrict__ hist) {
    int i = blockIdx.x * 256 + threadIdx.x;
    if (i < NN) atomicAdd(&hist[su[i] >> 16], 1u);
}

__global__ __launch_bounds__(1024) void scan_hi(const unsigned* __restrict__ hist, unsigned* __restrict__ selst) {
    __shared__ unsigned csum[1024];
    int c = threadIdx.x;
    unsigned s = 0;
    const unsigned* hp = hist + c * 64;
    for (int j = 0; j < 64; ++j) s += hp[j];
    csum[c] = s;
    __syncthreads();
    if (c == 0) {
        unsigned cum = 0;
        int chunk = 1023;
        for (; chunk > 0; --chunk) { if (cum + csum[chunk] >= KK) break; cum += csum[chunk]; }
        int b = chunk * 64 + 63;
        for (; b > chunk * 64; --b) { if (cum + hist[b] >= KK) break; cum += hist[b]; }
        selst[0] = (unsigned)b;   // hi bin of K-th largest
        selst[1] = cum;           // count strictly above hi bin
    }
}

__global__ __launch_bounds__(256) void hist_lo_k(const unsigned* __restrict__ su, const unsigned* __restrict__ selst,
                                                 unsigned* __restrict__ histlo) {
    int i = blockIdx.x * 256 + threadIdx.x;
    if (i < NN) {
        unsigned u = su[i];
        if ((u >> 16) == selst[0]) atomicAdd(&histlo[u & 0xffffu], 1u);
    }
}

__global__ __launch_bounds__(1024) void scan_lo(const unsigned* __restrict__ histlo, unsigned* __restrict__ selst) {
    __shared__ unsigned csum[1024];
    int c = threadIdx.x;
    unsigned s = 0;
    const unsigned* hp = histlo + c * 64;
    for (int j = 0; j < 64; ++j) s += hp[j];
    csum[c] = s;
    __syncthreads();
    if (c == 0) {
        unsigned cum = selst[1];
        int chunk = 1023;
        for (; chunk > 0; --chunk) { if (cum + csum[chunk] >= KK) break; cum += csum[chunk]; }
        int b = chunk * 64 + 63;
        for (; b > chunk * 64; --b) { if (cum + histlo[b] >= KK) break; cum += histlo[b]; }
        unsigned tu = (selst[0] << 16) | (unsigned)b;
        selst[2] = tu;          // K-th largest value (ordered uint)
        selst[3] = KK - cum;    // R = how many ties (==tu) to take, smallest indices first
    }
}

// ---------------- selection + per-column max of tanh(score)*h2 ----------------
__global__ __launch_bounds__(256) void select_colmax(const float* __restrict__ h2, const float* __restrict__ score,
                                                     const unsigned* __restrict__ su, const unsigned* __restrict__ selst,
                                                     unsigned* __restrict__ ties, unsigned* __restrict__ tiecnt,
                                                     unsigned* __restrict__ colmax) {
    unsigned tu = selst[2];
    int col = threadIdx.x & 127, sub = threadIdx.x >> 7;
    int r0 = blockIdx.x * 250, r1 = r0 + 250;
    float m = -INFINITY;
    for (int r = r0 + sub; r < r1; r += 2) {
        unsigned u = su[r];
        if (u > tu) {
            float g = tanhf(score[r]);
            m = fmaxf(m, g * h2[(size_t)r * 128 + col]);
        } else if (u == tu && col == 0) {
            unsigned p = atomicAdd(tiecnt, 1u);
            if (p < TIE_CAP) ties[p] = (unsigned)r;
        }
    }
    __shared__ float ls[256];
    ls[threadIdx.x] = m;
    __syncthreads();
    if (sub == 0) {
        float mm = fmaxf(ls[col], ls[col + 128]);
        if (mm > -INFINITY) atomicMax(&colmax[col], ford(mm));
    }
}

__global__ __launch_bounds__(128) void tie_resolve(const float* __restrict__ h2, const float* __restrict__ score,
                                                   const unsigned* __restrict__ selst, const unsigned* __restrict__ ties,
                                                   unsigned* __restrict__ colmax) {
    __shared__ unsigned chosen;
    int R = (int)selst[3];
    int tc = (int)selst[4];
    if (tc > TIE_CAP) tc = TIE_CAP;
    int t = threadIdx.x;
    unsigned last = 0;
    int iters = R < tc ? R : tc;
    for (int it = 0; it < iters; ++it) {
        if (t == 0) {
            unsigned best = 0xffffffffu;
            for (int j = 0; j < tc; ++j) {
                unsigned v = ties[j];
                if (v >= last && v < best) best = v;
            }
            chosen = best;
        }
        __syncthreads();
        unsigned row = chosen;
        if (row != 0xffffffffu) {
            float g = tanhf(score[row]);
            atomicMax(&colmax[t], ford(g * h2[(size_t)row * 128 + t]));
        }
        __syncthreads();
        if (t == 0) last = chosen + 1;
    }
}

// ---------------- head MLP (1 block) ----------------
__global__ __launch_bounds__(128) void head_k(const unsigned* __restrict__ colmax, const float* __restrict__ addf,
                                              const float* __restrict__ fc1w, const float* __restrict__ fc1b,
                                              const float* __restrict__ fa1, const float* __restrict__ w21,
                                              const float* __restrict__ b21, const float* __restrict__ fa2,
                                              const float* __restrict__ w22, const float* __restrict__ b22,
                                              const float* __restrict__ w3, const float* __restrict__ b3,
                                              const float* __restrict__ wm, const float* __restrict__ bm,
                                              float* __restrict__ out) {
    __shared__ float ag[132], xv[128], yv[128], red0[128], red1[128], red2[128];
    int t = threadIdx.x;
    ag[t] = fmaxf(unford(colmax[t]), unford(colmax[128 + t]));
    if (t < 4) ag[128 + t] = addf[t];
    __syncthreads();
    float s = fc1b[t];
    for (int k = 0; k < 132; ++k) s = fmaf(ag[k], fc1w[k * 128 + t], s);
    xv[t] = prelu(s, fa1[0]);
    __syncthreads();
    float s2 = b21[t];
    for (int k = 0; k < 128; ++k) s2 = fmaf(xv[k], w21[k * 128 + t], s2);
    yv[t] = prelu(s2, fa2[0]);
    __syncthreads();
    red0[t] = yv[t] * w22[t];
    red1[t] = xv[t] * w3[t];
    red2[t] = xv[t] * wm[t];
    __syncthreads();
    if (t == 0) {
        float r0 = 0.f, r1 = 0.f, r2 = 0.f;
        for (int k = 0; k < 128; ++k) { r0 += red0[k]; r1 += red1[k]; r2 += red2[k]; }
        out[0] = expf(r0 + b22[0]);
        out[1] = expf(r1 + b3[0]) * tanhf(r2 + bm[0]);
    }
}

extern "C" void kernel_launch(void* const* d_in, const int* in_sizes, int n_in,
                              void* d_out, int out_size, void* d_ws, size_t ws_size,
                              hipStream_t stream) {
    const float* Ax    = (const float*)d_in[0];
    const float* Gx    = (const float*)d_in[1];
    const float* addf  = (const float*)d_in[2];
    const float* gatw  = (const float*)d_in[3];
    const float* asrc  = (const float*)d_in[4];
    const float* adst  = (const float*)d_in[5];
    const float* gbias = (const float*)d_in[6];
    const float* bn1w  = (const float*)d_in[7];
    const float* bn1b  = (const float*)d_in[8];
    const float* pa1   = (const float*)d_in[9];
    const float* wl    = (const float*)d_in[10];
    const float* bl    = (const float*)d_in[11];
    const float* wr    = (const float*)d_in[12];
    const float* bn2w  = (const float*)d_in[13];
    const float* bn2b  = (const float*)d_in[14];
    const float* pa2   = (const float*)d_in[15];
    const float* wrel  = (const float*)d_in[16];
    const float* brel  = (const float*)d_in[17];
    const float* wroot = (const float*)d_in[18];
    const float* fc1w  = (const float*)d_in[19];
    const float* fc1b  = (const float*)d_in[20];
    const float* fa1   = (const float*)d_in[21];
    const float* w21   = (const float*)d_in[22];
    const float* b21   = (const float*)d_in[23];
    const float* fa2   = (const float*)d_in[24];
    const float* w22   = (const float*)d_in[25];
    const float* b22   = (const float*)d_in[26];
    const float* w3    = (const float*)d_in[27];
    const float* b3    = (const float*)d_in[28];
    const float* wm    = (const float*)d_in[29];
    const float* bm    = (const float*)d_in[30];
    const int*   Aei   = (const int*)d_in[31];
    const int*   Gei   = (const int*)d_in[32];
    float* out = (float*)d_out;

    char* wp = (char*)d_ws;
    auto alloc = [&](size_t bytes) -> char* {
        char* p = wp;
        wp += (bytes + 255) & ~(size_t)255;
        return p;
    };
    float*    big1   = (float*)alloc((size_t)NN * HH * 4);   // xw -> agg/h2 (in-place gemm)
    float*    big2   = (float*)alloc((size_t)NN * HH * 4);   // h1
    int*      csr    = (int*)alloc((size_t)EE * 4);
    float*    ealpha = (float*)alloc((size_t)EE * 4);
    int*      ptr    = (int*)alloc((NN + 1) * 4);
    int*      cur    = (int*)alloc(NN * 4);
    int*      deg    = (int*)alloc(NN * 4);
    float*    ssrc   = (float*)alloc(NN * 4);   // later reused as pr
    float*    sdst   = (float*)alloc(NN * 4);   // later reused as rootdot
    float*    score  = (float*)alloc(NN * 4);
    unsigned* su     = (unsigned*)alloc(NN * 4);
    float*    psum   = (float*)alloc(BN_BLOCKS * 128 * 4);
    float*    psq    = (float*)alloc(BN_BLOCKS * 128 * 4);
    float*    scale  = (float*)alloc(128 * 4);
    float*    shift  = (float*)alloc(128 * 4);
    unsigned* hist   = (unsigned*)alloc(65536 * 4);
    unsigned* histlo = (unsigned*)alloc(65536 * 4);
    unsigned* selst  = (unsigned*)alloc(8 * 4);
    unsigned* ties   = (unsigned*)alloc(TIE_CAP * 4);
    unsigned* colmax = (unsigned*)alloc(2 * 128 * 4);

    hipMemsetAsync(colmax, 0, 2 * 128 * 4, stream);

    for (int t = 0; t < 2; ++t) {
        const float* x   = (t == 0) ? Ax : Gx;
        const int* ei    = (t == 0) ? Aei : Gei;
        const int* esrc  = ei;
        const int* edst  = ei + EE;

        hipMemsetAsync(deg, 0, NN * 4, stream);
        hipMemsetAsync(hist, 0, 65536 * 4, stream);
        hipMemsetAsync(histlo, 0, 65536 * 4, stream);
        hipMemsetAsync(selst, 0, 8 * 4, stream);

        deg_hist<<<EE / 256, 256, 0, stream>>>(edst, deg);
        scan_ptr<<<1, 1024, 0, stream>>>(deg, ptr, cur);
        scatter_csr<<<EE / 256, 256, 0, stream>>>(esrc, edst, cur, csr);

        // GAT
        gemm128<<<(NN + 31) / 32, 256, 0, stream>>>(x, gatw, nullptr, big1, NN, 0, 0);
        att_scores<<<(NN + 3) / 4, 256, 0, stream>>>(big1, asrc, adst, ssrc, sdst);
        gat_agg<<<(NN + 3) / 4, 256, 0, stream>>>(big1, csr, ptr, ssrc, sdst, gbias, ealpha, big2);
        bn_stage1<<<BN_BLOCKS, 256, 0, stream>>>(big2, psum, psq);
        bn_stage2<<<1, 128, 0, stream>>>(psum, psq, bn1w, bn1b, scale, shift);
        bn_prelu_apply<<<NN * 128 / 4 / 256, 256, 0, stream>>>(big2, scale, shift, pa1);

        // SAGE: agg into big1 (xw dead), wl-gemm in place, wr-gemm accumulated
        max_agg<<<(NN + 3) / 4, 256, 0, stream>>>(big2, csr, ptr, big1);
        gemm128<<<(NN + 31) / 32, 256, 0, stream>>>(big1, wl, bl, big1, NN, 0, 1);
        gemm128<<<(NN + 31) / 32, 256, 0, stream>>>(big2, wr, nullptr, big1, NN, 1, 0);
        bn_stage1<<<BN_BLOCKS, 256, 0, stream>>>(big1, psum, psq);
        bn_stage2<<<1, 128, 0, stream>>>(psum, psq, bn2w, bn2b, scale, shift);
        bn_prelu_apply<<<NN * 128 / 4 / 256, 256, 0, stream>>>(big1, scale, shift, pa2);

        // SAGPool (linearized) -> column max
        node_dots<<<(NN + 3) / 4, 256, 0, stream>>>(big1, wrel, wroot, ssrc, sdst);
        score_k<<<(NN + 255) / 256, 256, 0, stream>>>(ssrc, sdst, csr, ptr, brel, score, su);
        hist_hi_k<<<(NN + 255) / 256, 256, 0, stream>>>(su, hist);
        scan_hi<<<1, 1024, 0, stream>>>(hist, selst);
        hist_lo_k<<<(NN + 255) / 256, 256, 0, stream>>>(su, selst, histlo);
        scan_lo<<<1, 1024, 0, stream>>>(histlo, selst);
        select_colmax<<<200, 256, 0, stream>>>(big1, score, su, selst, ties, selst + 4, colmax + t * 128);
        tie_resolve<<<1, 128, 0, stream>>>(big1, score, selst, ties, colmax + t * 128);
    }

    head_k<<<1, 128, 0, stream>>>(colmax, addf, fc1w, fc1b, fa1, w21, b21, fa2,
                                  w22, b22, w3, b3, wm, bm, out);
}

// Round 3
// 1367.610 us; speedup vs baseline: 1.5611x; 1.1958x over previous
//
#include <hip/hip_runtime.h>
#include <math.h>

#define NN 50000
#define EE 640000
#define HH 128
#define KK 25000
#define NEG_SLOPE 0.2f
#define TIE_CAP 4096
#define BN_BLOCKS 200
#define NSB 98   // ceil(NN/512)

__device__ __forceinline__ float lrelu(float x) { return x >= 0.f ? x : NEG_SLOPE * x; }
__device__ __forceinline__ float prelu(float x, float a) { return x >= 0.f ? x : a * x; }
__device__ __forceinline__ unsigned ford(float f) {
    unsigned u = __float_as_uint(f);
    return (u & 0x80000000u) ? ~u : (u | 0x80000000u);
}
__device__ __forceinline__ float unford(unsigned u) {
    return __uint_as_float((u & 0x80000000u) ? (u & 0x7fffffffu) : ~u);
}

// ---------------- CSR build ----------------
__global__ __launch_bounds__(256) void deg_hist(const int* __restrict__ dst, int* __restrict__ deg) {
    int i = blockIdx.x * 256 + threadIdx.x;
    if (i < EE) atomicAdd(&deg[dst[i]], 1);
}

// 3-stage parallel exclusive scan of deg -> ptr (and cur copy)
__global__ __launch_bounds__(512) void scan_s1(const int* __restrict__ deg, int* __restrict__ ptr,
                                               int* __restrict__ bsum) {
    __shared__ int tmp[512];
    int g = blockIdx.x * 512 + threadIdx.x;
    int v = (g < NN) ? deg[g] : 0;
    tmp[threadIdx.x] = v;
    __syncthreads();
    for (int o = 1; o < 512; o <<= 1) {
        int add = (threadIdx.x >= o) ? tmp[threadIdx.x - o] : 0;
        __syncthreads();
        tmp[threadIdx.x] += add;
        __syncthreads();
    }
    if (g < NN) ptr[g] = tmp[threadIdx.x] - v;   // local exclusive
    if (threadIdx.x == 511) bsum[blockIdx.x] = tmp[511];
}

__global__ __launch_bounds__(128) void scan_s2(int* __restrict__ bsum, int* __restrict__ ptr) {
    __shared__ int tmp[128];
    int t = threadIdx.x;
    int v = (t < NSB) ? bsum[t] : 0;
    tmp[t] = v;
    __syncthreads();
    for (int o = 1; o < 128; o <<= 1) {
        int add = (t >= o) ? tmp[t - o] : 0;
        __syncthreads();
        tmp[t] += add;
        __syncthreads();
    }
    if (t < NSB) bsum[t] = tmp[t] - v;           // exclusive block offsets
    if (t == 127) ptr[NN] = tmp[127];            // total (=EE)
}

__global__ __launch_bounds__(512) void scan_s3(int* __restrict__ ptr, const int* __restrict__ bsum,
                                               int* __restrict__ cur) {
    int g = blockIdx.x * 512 + threadIdx.x;
    if (g < NN) {
        int v = ptr[g] + bsum[blockIdx.x];
        ptr[g] = v;
        cur[g] = v;
    }
}

__global__ __launch_bounds__(256) void scatter_csr(const int* __restrict__ src, const int* __restrict__ dst,
                                                   int* __restrict__ cur, int* __restrict__ csr) {
    int i = blockIdx.x * 256 + threadIdx.x;
    if (i < EE) {
        int p = atomicAdd(&cur[dst[i]], 1);
        csr[p] = src[i];
    }
}

// ---------------- GEMM: C[n,128] = A[n,128] @ W[128,128] (+bias) (+C) ----------------
// K-tiled sW (16KB) + sA (16.5KB) = 32.5KB LDS -> 4 blocks/CU.
// Safe for C == A (rows staged to LDS before writes).
// Optional fused epilogue: per-row dots with asrc/adst (GAT attention scores);
// only valid when accflag==0 && biasflag==0.
__global__ __launch_bounds__(256) void gemm128(const float* __restrict__ A, const float* __restrict__ W,
                                               const float* __restrict__ bias, float* __restrict__ C,
                                               int n, int accflag, int biasflag,
                                               const float* __restrict__ asrc, const float* __restrict__ adst,
                                               float* __restrict__ ssrc_o, float* __restrict__ sdst_o) {
    __shared__ float sW[32 * 128];   // one K-tile
    __shared__ float sA[32 * 132];
    int row0 = blockIdx.x * 32;
    int nrows = n - row0; if (nrows > 32) nrows = 32;
    for (int i = threadIdx.x; i < 1024; i += 256) {
        int r = i >> 5, c4 = i & 31;
        if (r < nrows)
            *((float4*)(sA + r * 132 + c4 * 4)) = ((const float4*)(A + (size_t)(row0 + r) * 128))[c4];
    }
    int tr = threadIdx.x >> 4;           // rows 2tr, 2tr+1
    int c0 = (threadIdx.x & 15) * 4;
    float a00[4] = {0,0,0,0}, a01[4] = {0,0,0,0}, a10[4] = {0,0,0,0}, a11[4] = {0,0,0,0};
    const float* a0p = sA + (tr * 2) * 132;
    const float* a1p = a0p + 132;
    for (int kt = 0; kt < 4; ++kt) {
        __syncthreads();                 // sA ready (kt=0) / prev tile consumed (kt>0)
        for (int i = threadIdx.x; i < 1024; i += 256)
            ((float4*)sW)[i] = ((const float4*)W)[kt * 1024 + i];
        __syncthreads();
        int kb = kt * 32;
        for (int k = 0; k < 32; ++k) {
            float a0 = a0p[kb + k], a1 = a1p[kb + k];
            float4 w0 = *(const float4*)(sW + k * 128 + c0);
            float4 w1 = *(const float4*)(sW + k * 128 + c0 + 64);
            a00[0] = fmaf(a0, w0.x, a00[0]); a00[1] = fmaf(a0, w0.y, a00[1]);
            a00[2] = fmaf(a0, w0.z, a00[2]); a00[3] = fmaf(a0, w0.w, a00[3]);
            a01[0] = fmaf(a0, w1.x, a01[0]); a01[1] = fmaf(a0, w1.y, a01[1]);
            a01[2] = fmaf(a0, w1.z, a01[2]); a01[3] = fmaf(a0, w1.w, a01[3]);
            a10[0] = fmaf(a1, w0.x, a10[0]); a10[1] = fmaf(a1, w0.y, a10[1]);
            a10[2] = fmaf(a1, w0.z, a10[2]); a10[3] = fmaf(a1, w0.w, a10[3]);
            a11[0] = fmaf(a1, w1.x, a11[0]); a11[1] = fmaf(a1, w1.y, a11[1]);
            a11[2] = fmaf(a1, w1.z, a11[2]); a11[3] = fmaf(a1, w1.w, a11[3]);
        }
    }
    float b0[4] = {0,0,0,0}, b1[4] = {0,0,0,0};
    if (biasflag) {
        #pragma unroll
        for (int u = 0; u < 4; ++u) { b0[u] = bias[c0 + u]; b1[u] = bias[c0 + 64 + u]; }
    }
    #pragma unroll
    for (int rr = 0; rr < 2; ++rr) {
        int r = row0 + tr * 2 + rr;
        if (r < n) {
            float* op = C + (size_t)r * 128;
            float vlo[4], vhi[4];
            #pragma unroll
            for (int u = 0; u < 4; ++u) {
                vlo[u] = (rr ? a10[u] : a00[u]) + b0[u];
                vhi[u] = (rr ? a11[u] : a01[u]) + b1[u];
            }
            if (accflag) {
                float4 o0 = *(float4*)(op + c0);
                float4 o1 = *(float4*)(op + c0 + 64);
                vlo[0] += o0.x; vlo[1] += o0.y; vlo[2] += o0.z; vlo[3] += o0.w;
                vhi[0] += o1.x; vhi[1] += o1.y; vhi[2] += o1.z; vhi[3] += o1.w;
            }
            *(float4*)(op + c0)      = make_float4(vlo[0], vlo[1], vlo[2], vlo[3]);
            *(float4*)(op + c0 + 64) = make_float4(vhi[0], vhi[1], vhi[2], vhi[3]);
        }
    }
    if (ssrc_o) {  // fused attention-score dots (raw accumulators: no bias/acc in this path)
        float ps0 = 0.f, pd0 = 0.f, ps1 = 0.f, pd1 = 0.f;
        #pragma unroll
        for (int u = 0; u < 4; ++u) {
            float w0s = asrc[c0 + u], w1s = asrc[c0 + 64 + u];
            float w0d = adst[c0 + u], w1d = adst[c0 + 64 + u];
            ps0 += a00[u] * w0s + a01[u] * w1s;
            pd0 += a00[u] * w0d + a01[u] * w1d;
            ps1 += a10[u] * w0s + a11[u] * w1s;
            pd1 += a10[u] * w0d + a11[u] * w1d;
        }
        #pragma unroll
        for (int o = 1; o < 16; o <<= 1) {
            ps0 += __shfl_xor(ps0, o); pd0 += __shfl_xor(pd0, o);
            ps1 += __shfl_xor(ps1, o); pd1 += __shfl_xor(pd1, o);
        }
        if ((threadIdx.x & 15) == 0) {
            int r = row0 + tr * 2;
            if (r < n)     { ssrc_o[r] = ps0;     sdst_o[r] = pd0; }
            if (r + 1 < n) { ssrc_o[r + 1] = ps1; sdst_o[r + 1] = pd1; }
        }
    }
}

// ---------------- GAT aggregation (online softmax, single edge sweep + feature pass) ----------------
__global__ __launch_bounds__(256) void gat_agg(const float* __restrict__ xw, const int* __restrict__ csr,
                                               const int* __restrict__ ptr, const float* __restrict__ ssrc,
                                               const float* __restrict__ sdst, const float* __restrict__ bias,
                                               float* __restrict__ ealpha, float* __restrict__ out) {
    int wid = (blockIdx.x * 256 + threadIdx.x) >> 6;
    int lane = threadIdx.x & 63;
    if (wid >= NN) return;
    int s = ptr[wid], e = ptr[wid + 1];
    float sd = sdst[wid];
    float selfval = lrelu(ssrc[wid] + sd);
    float m = -1e30f, sum = 0.f;
    if (lane == 0) { m = selfval; sum = 1.f; }
    for (int i = s + lane; i < e; i += 64) {
        float v = lrelu(ssrc[csr[i]] + sd);
        ealpha[i] = v;
        float nm = fmaxf(m, v);
        sum = sum * __expf(m - nm) + __expf(v - nm);
        m = nm;
    }
    #pragma unroll
    for (int o = 1; o < 64; o <<= 1) {
        float om = __shfl_xor(m, o);
        float os = __shfl_xor(sum, o);
        float nm = fmaxf(m, om);
        sum = sum * __expf(m - nm) + os * __expf(om - nm);
        m = nm;
    }
    float inv = 1.f / sum;
    asm volatile("s_waitcnt vmcnt(0)" ::: "memory");   // ealpha stores visible before cross-lane reads
    float aself = __expf(selfval - m) * inv;
    float f0 = aself * xw[(size_t)wid * 128 + lane];
    float f1 = aself * xw[(size_t)wid * 128 + lane + 64];
    int i = s;
    for (; i + 4 <= e; i += 4) {
        int s0 = csr[i], s1 = csr[i + 1], s2 = csr[i + 2], s3 = csr[i + 3];
        float al0 = __expf(ealpha[i] - m) * inv,     al1 = __expf(ealpha[i + 1] - m) * inv;
        float al2 = __expf(ealpha[i + 2] - m) * inv, al3 = __expf(ealpha[i + 3] - m) * inv;
        const float* p0 = xw + (size_t)s0 * 128;
        const float* p1 = xw + (size_t)s1 * 128;
        const float* p2 = xw + (size_t)s2 * 128;
        const float* p3 = xw + (size_t)s3 * 128;
        float x00 = p0[lane], x01 = p0[lane + 64];
        float x10 = p1[lane], x11 = p1[lane + 64];
        float x20 = p2[lane], x21 = p2[lane + 64];
        float x30 = p3[lane], x31 = p3[lane + 64];
        f0 = fmaxf(fmaxf(fmaxf(fmaxf(f0, al0 * x00), al1 * x10), al2 * x20), al3 * x30);
        f1 = fmaxf(fmaxf(fmaxf(fmaxf(f1, al0 * x01), al1 * x11), al2 * x21), al3 * x31);
    }
    for (; i < e; ++i) {
        int src = csr[i];
        float a = __expf(ealpha[i] - m) * inv;
        f0 = fmaxf(f0, a * xw[(size_t)src * 128 + lane]);
        f1 = fmaxf(f1, a * xw[(size_t)src * 128 + lane + 64]);
    }
    out[(size_t)wid * 128 + lane] = f0 + bias[lane];
    out[(size_t)wid * 128 + lane + 64] = f1 + bias[lane + 64];
}

// ---------------- BatchNorm (batch stats) + PReLU ----------------
__global__ __launch_bounds__(256) void bn_stage1(const float* __restrict__ x, float* __restrict__ psum,
                                                 float* __restrict__ psq) {
    int col = threadIdx.x & 127, sub = threadIdx.x >> 7;
    int r0 = blockIdx.x * 250, r1 = r0 + 250;
    float s = 0.f, q = 0.f;
    for (int r = r0 + sub; r < r1; r += 2) {
        float v = x[(size_t)r * 128 + col];
        s += v;
        q = fmaf(v, v, q);
    }
    __shared__ float ls[256], lq[256];
    ls[threadIdx.x] = s; lq[threadIdx.x] = q;
    __syncthreads();
    if (sub == 0) {
        psum[blockIdx.x * 128 + col] = ls[col] + ls[col + 128];
        psq[blockIdx.x * 128 + col] = lq[col] + lq[col + 128];
    }
}

__global__ __launch_bounds__(128) void bn_stage2(const float* __restrict__ psum, const float* __restrict__ psq,
                                                 const float* __restrict__ w, const float* __restrict__ b,
                                                 float* __restrict__ scale, float* __restrict__ shift) {
    int c = threadIdx.x;
    double s = 0.0, q = 0.0;
    for (int i = 0; i < BN_BLOCKS; ++i) { s += (double)psum[i * 128 + c]; q += (double)psq[i * 128 + c]; }
    double mu = s / NN;
    double var = q / NN - mu * mu;
    if (var < 0.0) var = 0.0;
    float rs = (float)(1.0 / sqrt(var + 1e-5));
    float sc = rs * w[c];
    scale[c] = sc;
    shift[c] = b[c] - (float)mu * sc;
}

__global__ __launch_bounds__(256) void bn_prelu_apply(float* __restrict__ x, const float* __restrict__ scale,
                                                      const float* __restrict__ shift, const float* __restrict__ pa) {
    int i = blockIdx.x * 256 + threadIdx.x;   // grid covers NN*128/4 exactly
    float a = pa[0];
    float4 v = ((float4*)x)[i];
    int c = (i * 4) & 127;
    v.x = v.x * scale[c]     + shift[c];     v.x = prelu(v.x, a);
    v.y = v.y * scale[c + 1] + shift[c + 1]; v.y = prelu(v.y, a);
    v.z = v.z * scale[c + 2] + shift[c + 2]; v.z = prelu(v.z, a);
    v.w = v.w * scale[c + 3] + shift[c + 3]; v.w = prelu(v.w, a);
    ((float4*)x)[i] = v;
}

// BN+PReLU fused with SAGPool per-node dots (wave handles a row pair; 32-lane reduce)
__global__ __launch_bounds__(256) void bn_prelu_dots(float* __restrict__ x, const float* __restrict__ scale,
                                                     const float* __restrict__ shift, const float* __restrict__ pa,
                                                     const float* __restrict__ wrel, const float* __restrict__ wroot,
                                                     float* __restrict__ pr, float* __restrict__ rootdot) {
    int gw = (blockIdx.x * 256 + threadIdx.x) >> 6;   // wave id == row pair
    int lane = threadIdx.x & 63;
    if (gw >= NN / 2) return;
    int row = gw * 2 + (lane >> 5);
    int cq = lane & 31;
    int c = cq * 4;
    float a = pa[0];
    float4 v = ((float4*)x)[(size_t)row * 32 + cq];
    v.x = prelu(v.x * scale[c]     + shift[c],     a);
    v.y = prelu(v.y * scale[c + 1] + shift[c + 1], a);
    v.z = prelu(v.z * scale[c + 2] + shift[c + 2], a);
    v.w = prelu(v.w * scale[c + 3] + shift[c + 3], a);
    ((float4*)x)[(size_t)row * 32 + cq] = v;
    float p = v.x * wrel[c] + v.y * wrel[c + 1] + v.z * wrel[c + 2] + v.w * wrel[c + 3];
    float r = v.x * wroot[c] + v.y * wroot[c + 1] + v.z * wroot[c + 2] + v.w * wroot[c + 3];
    #pragma unroll
    for (int o = 1; o < 32; o <<= 1) { p += __shfl_xor(p, o); r += __shfl_xor(r, o); }
    if (cq == 0) { pr[row] = p; rootdot[row] = r; }
}

// ---------------- SAGE max-aggregation ----------------
__global__ __launch_bounds__(256) void max_agg(const float* __restrict__ h1, const int* __restrict__ csr,
                                               const int* __restrict__ ptr, float* __restrict__ agg) {
    int wid = (blockIdx.x * 256 + threadIdx.x) >> 6;
    int lane = threadIdx.x & 63;
    if (wid >= NN) return;
    int s = ptr[wid], e = ptr[wid + 1];
    float m0 = -INFINITY, m1 = -INFINITY;
    int i = s;
    for (; i + 4 <= e; i += 4) {
        int s0 = csr[i], s1 = csr[i + 1], s2 = csr[i + 2], s3 = csr[i + 3];
        const float* p0 = h1 + (size_t)s0 * 128;
        const float* p1 = h1 + (size_t)s1 * 128;
        const float* p2 = h1 + (size_t)s2 * 128;
        const float* p3 = h1 + (size_t)s3 * 128;
        float x00 = p0[lane], x01 = p0[lane + 64];
        float x10 = p1[lane], x11 = p1[lane + 64];
        float x20 = p2[lane], x21 = p2[lane + 64];
        float x30 = p3[lane], x31 = p3[lane + 64];
        m0 = fmaxf(fmaxf(fmaxf(fmaxf(m0, x00), x10), x20), x30);
        m1 = fmaxf(fmaxf(fmaxf(fmaxf(m1, x01), x11), x21), x31);
    }
    for (; i < e; ++i) {
        int src = csr[i];
        m0 = fmaxf(m0, h1[(size_t)src * 128 + lane]);
        m1 = fmaxf(m1, h1[(size_t)src * 128 + lane + 64]);
    }
    if (s == e) { m0 = 0.f; m1 = 0.f; }
    agg[(size_t)wid * 128 + lane] = m0;
    agg[(size_t)wid * 128 + lane + 64] = m1;
}

// ---------------- SAGPool score (4B/edge gather) + fused hi-histogram ----------------
__global__ __launch_bounds__(256) void score_k(const float* __restrict__ pr, const float* __restrict__ rootdot,
                                               const int* __restrict__ csr, const int* __restrict__ ptr,
                                               const float* __restrict__ brel, float* __restrict__ score,
                                               unsigned* __restrict__ su, unsigned* __restrict__ hist) {
    int d = blockIdx.x * 256 + threadIdx.x;
    if (d >= NN) return;
    int s = ptr[d], e = ptr[d + 1];
    float acc = 0.f;
    for (int i = s; i < e; ++i) acc += pr[csr[i]];
    float sc = acc + rootdot[d] + brel[0];
    score[d] = sc;
    unsigned u = ford(sc);
    su[d] = u;
    atomicAdd(&hist[u >> 16], 1u);
}

// ---------------- exact K-th largest (radix 2x16-bit) ----------------
__global__ __launch_bounds__(1024) void scan_hi(const unsigned* __restrict__ hist, unsigned* __restrict__ selst) {
    __shared__ unsigned csum[1024];
    int c = threadIdx.x;
    unsigned s = 0;
    const unsigned* hp = hist + c * 64;
    for (int j = 0; j < 64; ++j) s += hp[j];
    csum[c] = s;
    __syncthreads();
    if (c == 0) {
        unsigned cum = 0;
        int chunk = 1023;
        for (; chunk > 0; --chunk) { if (cum + csum[chunk] >= KK) break; cum += csum[chunk]; }
        int b = chunk * 64 + 63;
        for (; b > chunk * 64; --b) { if (cum + hist[b] >= KK) break; cum += hist[b]; }
        selst[0] = (unsigned)b;
        selst[1] = cum;
    }
}

__global__ __launch_bounds__(256) void hist_lo_k(const unsigned* __restrict__ su, const unsigned* __restrict__ selst,
                                                 unsigned* __restrict__ histlo) {
    int i = blockIdx.x * 256 + threadIdx.x;
    if (i < NN) {
        unsigned u = su[i];
        if ((u >> 16) == selst[0]) atomicAdd(&histlo[u & 0xffffu], 1u);
    }
}

__global__ __launch_bounds__(1024) void scan_lo(const unsigned* __restrict__ histlo, unsigned* __restrict__ selst) {
    __shared__ unsigned csum[1024];
    int c = threadIdx.x;
    unsigned s = 0;
    const unsigned* hp = histlo + c * 64;
    for (int j = 0; j < 64; ++j) s += hp[j];
    csum[c] = s;
    __syncthreads();
    if (c == 0) {
        unsigned cum = selst[1];
        int chunk = 1023;
        for (; chunk > 0; --chunk) { if (cum + csum[chunk] >= KK) break; cum += csum[chunk]; }
        int b = chunk * 64 + 63;
        for (; b > chunk * 64; --b) { if (cum + histlo[b] >= KK) break; cum += histlo[b]; }
        unsigned tu = (selst[0] << 16) | (unsigned)b;
        selst[2] = tu;
        selst[3] = KK - cum;
    }
}

// ---------------- selection + per-column max of tanh(score)*h2 ----------------
__global__ __launch_bounds__(256) void select_colmax(const float* __restrict__ h2, const float* __restrict__ score,
                                                     const unsigned* __restrict__ su, const unsigned* __restrict__ selst,
                                                     unsigned* __restrict__ ties, unsigned* __restrict__ tiecnt,
                                                     unsigned* __restrict__ colmax) {
    unsigned tu = selst[2];
    int col = threadIdx.x & 127, sub = threadIdx.x >> 7;
    int r0 = blockIdx.x * 250, r1 = r0 + 250;
    float m = -INFINITY;
    for (int r = r0 + sub; r < r1; r += 2) {
        unsigned u = su[r];
        if (u > tu) {
            float g = tanhf(score[r]);
            m = fmaxf(m, g * h2[(size_t)r * 128 + col]);
        } else if (u == tu && col == 0) {
            unsigned p = atomicAdd(tiecnt, 1u);
            if (p < TIE_CAP) ties[p] = (unsigned)r;
        }
    }
    __shared__ float ls[256];
    ls[threadIdx.x] = m;
    __syncthreads();
    if (sub == 0) {
        float mm = fmaxf(ls[col], ls[col + 128]);
        if (mm > -INFINITY) atomicMax(&colmax[col], ford(mm));
    }
}

__global__ __launch_bounds__(128) void tie_resolve(const float* __restrict__ h2, const float* __restrict__ score,
                                                   const unsigned* __restrict__ selst, const unsigned* __restrict__ ties,
                                                   unsigned* __restrict__ colmax) {
    __shared__ unsigned chosen;
    int R = (int)selst[3];
    int tc = (int)selst[4];
    if (tc > TIE_CAP) tc = TIE_CAP;
    int t = threadIdx.x;
    unsigned last = 0;
    int iters = R < tc ? R : tc;
    for (int it = 0; it < iters; ++it) {
        if (t == 0) {
            unsigned best = 0xffffffffu;
            for (int j = 0; j < tc; ++j) {
                unsigned v = ties[j];
                if (v >= last && v < best) best = v;
            }
            chosen = best;
        }
        __syncthreads();
        unsigned row = chosen;
        if (row != 0xffffffffu) {
            float g = tanhf(score[row]);
            atomicMax(&colmax[t], ford(g * h2[(size_t)row * 128 + t]));
        }
        __syncthreads();
        if (t == 0) last = chosen + 1;
    }
}

// ---------------- head MLP (1 block) ----------------
__global__ __launch_bounds__(128) void head_k(const unsigned* __restrict__ colmax, const float* __restrict__ addf,
                                              const float* __restrict__ fc1w, const float* __restrict__ fc1b,
                                              const float* __restrict__ fa1, const float* __restrict__ w21,
                                              const float* __restrict__ b21, const float* __restrict__ fa2,
                                              const float* __restrict__ w22, const float* __restrict__ b22,
                                              const float* __restrict__ w3, const float* __restrict__ b3,
                                              const float* __restrict__ wm, const float* __restrict__ bm,
                                              float* __restrict__ out) {
    __shared__ float ag[132], xv[128], yv[128], red0[128], red1[128], red2[128];
    int t = threadIdx.x;
    ag[t] = fmaxf(unford(colmax[t]), unford(colmax[128 + t]));
    if (t < 4) ag[128 + t] = addf[t];
    __syncthreads();
    float s = fc1b[t];
    for (int k = 0; k < 132; ++k) s = fmaf(ag[k], fc1w[k * 128 + t], s);
    xv[t] = prelu(s, fa1[0]);
    __syncthreads();
    float s2 = b21[t];
    for (int k = 0; k < 128; ++k) s2 = fmaf(xv[k], w21[k * 128 + t], s2);
    yv[t] = prelu(s2, fa2[0]);
    __syncthreads();
    red0[t] = yv[t] * w22[t];
    red1[t] = xv[t] * w3[t];
    red2[t] = xv[t] * wm[t];
    __syncthreads();
    if (t == 0) {
        float r0 = 0.f, r1 = 0.f, r2 = 0.f;
        for (int k = 0; k < 128; ++k) { r0 += red0[k]; r1 += red1[k]; r2 += red2[k]; }
        out[0] = expf(r0 + b22[0]);
        out[1] = expf(r1 + b3[0]) * tanhf(r2 + bm[0]);
    }
}

extern "C" void kernel_launch(void* const* d_in, const int* in_sizes, int n_in,
                              void* d_out, int out_size, void* d_ws, size_t ws_size,
                              hipStream_t stream) {
    const float* Ax    = (const float*)d_in[0];
    const float* Gx    = (const float*)d_in[1];
    const float* addf  = (const float*)d_in[2];
    const float* gatw  = (const float*)d_in[3];
    const float* asrc  = (const float*)d_in[4];
    const float* adst  = (const float*)d_in[5];
    const float* gbias = (const float*)d_in[6];
    const float* bn1w  = (const float*)d_in[7];
    const float* bn1b  = (const float*)d_in[8];
    const float* pa1   = (const float*)d_in[9];
    const float* wl    = (const float*)d_in[10];
    const float* bl    = (const float*)d_in[11];
    const float* wr    = (const float*)d_in[12];
    const float* bn2w  = (const float*)d_in[13];
    const float* bn2b  = (const float*)d_in[14];
    const float* pa2   = (const float*)d_in[15];
    const float* wrel  = (const float*)d_in[16];
    const float* brel  = (const float*)d_in[17];
    const float* wroot = (const float*)d_in[18];
    const float* fc1w  = (const float*)d_in[19];
    const float* fc1b  = (const float*)d_in[20];
    const float* fa1   = (const float*)d_in[21];
    const float* w21   = (const float*)d_in[22];
    const float* b21   = (const float*)d_in[23];
    const float* fa2   = (const float*)d_in[24];
    const float* w22   = (const float*)d_in[25];
    const float* b22   = (const float*)d_in[26];
    const float* w3    = (const float*)d_in[27];
    const float* b3    = (const float*)d_in[28];
    const float* wm    = (const float*)d_in[29];
    const float* bm    = (const float*)d_in[30];
    const int*   Aei   = (const int*)d_in[31];
    const int*   Gei   = (const int*)d_in[32];
    float* out = (float*)d_out;

    char* wp = (char*)d_ws;
    auto alloc = [&](size_t bytes) -> char* {
        char* p = wp;
        wp += (bytes + 255) & ~(size_t)255;
        return p;
    };
    float*    big1   = (float*)alloc((size_t)NN * HH * 4);   // xw -> agg/h2 (in-place gemm)
    float*    big2   = (float*)alloc((size_t)NN * HH * 4);   // h1
    int*      csr    = (int*)alloc((size_t)EE * 4);
    float*    ealpha = (float*)alloc((size_t)EE * 4);
    int*      ptr    = (int*)alloc((NN + 1) * 4);
    int*      cur    = (int*)alloc(NN * 4);
    int*      deg    = (int*)alloc(NN * 4);
    int*      bsum   = (int*)alloc(NSB * 4);
    float*    ssrc   = (float*)alloc(NN * 4);   // reused as pr
    float*    sdst   = (float*)alloc(NN * 4);   // reused as rootdot
    float*    score  = (float*)alloc(NN * 4);
    unsigned* su     = (unsigned*)alloc(NN * 4);
    float*    psum   = (float*)alloc(BN_BLOCKS * 128 * 4);
    float*    psq    = (float*)alloc(BN_BLOCKS * 128 * 4);
    float*    scale  = (float*)alloc(128 * 4);
    float*    shift  = (float*)alloc(128 * 4);
    unsigned* hist   = (unsigned*)alloc(65536 * 4);   // hist..selst contiguous: one memset
    unsigned* histlo = (unsigned*)alloc(65536 * 4);
    unsigned* selst  = (unsigned*)alloc(8 * 4);
    unsigned* ties   = (unsigned*)alloc(TIE_CAP * 4);
    unsigned* colmax = (unsigned*)alloc(2 * 128 * 4);

    hipMemsetAsync(colmax, 0, 2 * 128 * 4, stream);

    for (int t = 0; t < 2; ++t) {
        const float* x   = (t == 0) ? Ax : Gx;
        const int* ei    = (t == 0) ? Aei : Gei;
        const int* esrc  = ei;
        const int* edst  = ei + EE;

        hipMemsetAsync(deg, 0, NN * 4, stream);
        hipMemsetAsync(hist, 0, 2 * 65536 * 4 + 256, stream);   // hist + histlo + selst(+tiecnt)

        deg_hist<<<EE / 256, 256, 0, stream>>>(edst, deg);
        scan_s1<<<NSB, 512, 0, stream>>>(deg, ptr, bsum);
        scan_s2<<<1, 128, 0, stream>>>(bsum, ptr);
        scan_s3<<<NSB, 512, 0, stream>>>(ptr, bsum, cur);
        scatter_csr<<<EE / 256, 256, 0, stream>>>(esrc, edst, cur, csr);

        // GAT (attention dots fused into gemm epilogue)
        gemm128<<<(NN + 31) / 32, 256, 0, stream>>>(x, gatw, nullptr, big1, NN, 0, 0,
                                                    asrc, adst, ssrc, sdst);
        gat_agg<<<(NN + 3) / 4, 256, 0, stream>>>(big1, csr, ptr, ssrc, sdst, gbias, ealpha, big2);
        bn_stage1<<<BN_BLOCKS, 256, 0, stream>>>(big2, psum, psq);
        bn_stage2<<<1, 128, 0, stream>>>(psum, psq, bn1w, bn1b, scale, shift);
        bn_prelu_apply<<<NN * 128 / 4 / 256, 256, 0, stream>>>(big2, scale, shift, pa1);

        // SAGE: agg into big1 (xw dead), wl-gemm in place, wr-gemm accumulated
        max_agg<<<(NN + 3) / 4, 256, 0, stream>>>(big2, csr, ptr, big1);
        gemm128<<<(NN + 31) / 32, 256, 0, stream>>>(big1, wl, bl, big1, NN, 0, 1,
                                                    nullptr, nullptr, nullptr, nullptr);
        gemm128<<<(NN + 31) / 32, 256, 0, stream>>>(big2, wr, nullptr, big1, NN, 1, 0,
                                                    nullptr, nullptr, nullptr, nullptr);
        bn_stage1<<<BN_BLOCKS, 256, 0, stream>>>(big1, psum, psq);
        bn_stage2<<<1, 128, 0, stream>>>(psum, psq, bn2w, bn2b, scale, shift);
        bn_prelu_dots<<<(NN / 2 + 3) / 4, 256, 0, stream>>>(big1, scale, shift, pa2,
                                                            wrel, wroot, ssrc, sdst);

        // SAGPool (linearized) -> column max
        score_k<<<(NN + 255) / 256, 256, 0, stream>>>(ssrc, sdst, csr, ptr, brel, score, su, hist);
        scan_hi<<<1, 1024, 0, stream>>>(hist, selst);
        hist_lo_k<<<(NN + 255) / 256, 256, 0, stream>>>(su, selst, histlo);
        scan_lo<<<1, 1024, 0, stream>>>(histlo, selst);
        select_colmax<<<200, 256, 0, stream>>>(big1, score, su, selst, ties, selst + 4, colmax + t * 128);
        tie_resolve<<<1, 128, 0, stream>>>(big1, score, selst, ties, colmax + t * 128);
    }

    head_k<<<1, 128, 0, stream>>>(colmax, addf, fc1w, fc1b, fa1, w21, b21, fa2,
                                  w22, b22, w3, b3, wm, bm, out);
}